// Round 13
// baseline (443.313 us; speedup 1.0000x reference)
//
#include <hip/hip_runtime.h>

// ---------------------------------------------------------------------------
// Elastic 2D velocity-stress staggered FD + C-PML, 2 shots, 128 steps.
// Round 22 == R20 resubmitted (best stable kernel; 371us dispatch, 438us
// bench, passed, clean profile).
//  - R21 (lgkm-only end-of-step barrier): falsified the drain theory --
//    typical dispatch +10us AND one 36.5ms pathological stall outlier
//    (tail-latency hazard in the lock-free protocol) -> reverted.
// Model state (6 controlled experiments, 5 counter-exact):
//  dur/step 2.90us = compute ~1.3 (lockstep PML edges; occupancy exhausted
//  R14/15) + traffic ~0.9 (16B/cell coalesced floor, WRITE_SIZE == ideal)
//  + sync ~0.7 (arrival-skew; 3 barriers = phase-structure minimum).
// Ladder: 934 -> 822 (R10 pull batching) -> 776 (1024thr+inline init) ->
//  636 (R18 2-word packed publish) -> 479 (R19 one 16B store/cell) ->
//  438 (R20 16B-stride coalesced records). 2.13x total.
// ---------------------------------------------------------------------------

typedef unsigned long long ull;
typedef __attribute__((ext_vector_type(4))) unsigned int uint4v;

#define NYI   300
#define NXI   300
#define PML   20
#define NYP   340
#define NXP   340
#define NT    128
#define DXC   5.0f
#define DTC   0.001f
#define NSHOT 2
#define NREC  32
#define C1C   (9.0f / 8.0f)
#define C2C   (-1.0f / 24.0f)
#define RDX   (1.0f / 5.0f)

#define PITCH   344
#define FSTRIDE (NYP * PITCH)
#define RECU    2            /* ulls per cell record (16B, packed) */

// tile grid per shot: 8 x 16 tiles
#define TX 8
#define TY 16
#define TW 43
#define TH 22
#define MH 30
#define MW 52
#define VH 26
#define VW 48
#define IH 22
#define IW 44

#define NTHR 1024

// 16B system-coherent store: one fabric transaction per cell record; with
// 16B-stride records adjacent lanes are contiguous -> intra-wave coalescing.
__device__ __forceinline__ void cstore16(ull* p, ull w0, ull w1) {
    uint4v v;
    v.x = (unsigned)w0; v.y = (unsigned)(w0 >> 32);
    v.z = (unsigned)w1; v.w = (unsigned)(w1 >> 32);
    asm volatile("global_store_dwordx4 %0, %1, off sc0 sc1"
                 :: "v"(p), "v"(v) : "memory");
}
// 16B system-coherent load, issue-only (no wait): latency hides under compute.
__device__ __forceinline__ uint4v cload16_issue(const ull* p) {
    uint4v r;
    asm volatile("global_load_dwordx4 %0, %1, off sc0 sc1"
                 : "=v"(r) : "v"(p) : "memory");
    return r;
}
// Wait for the issued load; "+v" makes every later use depend on this asm.
__device__ __forceinline__ void cload16_wait(uint4v& r) {
    asm volatile("s_waitcnt vmcnt(0)" : "+v"(r) :: "memory");
}
// Combined load+wait for the spin path.
__device__ __forceinline__ uint4v cload16_sync(const ull* p) {
    uint4v r;
    asm volatile("global_load_dwordx4 %0, %1, off sc0 sc1\n\ts_waitcnt vmcnt(0)"
                 : "=v"(r) : "v"(p) : "memory");
    return r;
}

__device__ __forceinline__ float decay_at(int idx) {
    float fx = (float)idx;
    float lo = fminf(fmaxf(((float)PML - fx) / (float)PML, 0.0f), 1.0f);
    float hi = fminf(fmaxf((fx - (float)(NYP - 1 - PML)) / (float)PML, 0.0f), 1.0f);
    float mx = fmaxf(lo, hi);
    float d0 = 3.0f * 2000.0f / (2.0f * (float)PML * DXC) * logf(1.0f / 1e-6f);
    return expf(-d0 * mx * mx * DTC);
}
__device__ __forceinline__ int clampi(int v, int hi) {
    return v < 0 ? 0 : (v > hi ? hi : v);
}

__global__ void init_params_kernel(const float* __restrict__ lamb,
                                   const float* __restrict__ mu,
                                   const float* __restrict__ buo,
                                   float* __restrict__ params) {
    int x = blockIdx.x * blockDim.x + threadIdx.x;
    int y = blockIdx.y;
    if (x >= NXP || y >= NYP) return;
    int cy = y - PML; cy = cy < 0 ? 0 : (cy > NYI - 1 ? NYI - 1 : cy);
    int cx = x - PML; cx = cx < 0 ? 0 : (cx > NXI - 1 ? NXI - 1 : cx);
    float l = lamb[cy * NXI + cx];
    float m = mu[cy * NXI + cx];
    float b = buo[cy * NXI + cx];
    int idx = y * PITCH + x;
    params[0 * FSTRIDE + idx] = l;
    params[1 * FSTRIDE + idx] = l + 2.0f * m;
    params[2 * FSTRIDE + idx] = m;
    params[3 * FSTRIDE + idx] = b;
}

__global__ void init_decay_kernel(float* __restrict__ bdec) {
    int i = blockIdx.x * blockDim.x + threadIdx.x;
    if (i >= NYP + NXP) return;
    int idx = (i < NYP) ? i : i - NYP;
    bdec[i] = decay_at(idx);
}

__global__ __launch_bounds__(NTHR)
void persist6_kernel(ull* __restrict__ strips, const float* __restrict__ lamb,
                     const float* __restrict__ mu, const float* __restrict__ buo,
                     const float* __restrict__ amps,
                     const int* __restrict__ sloc, const int* __restrict__ rloc,
                     float* __restrict__ out) {
    __shared__ float syyR[MH][MW], sxxR[MH][MW], sxyR[MH][MW];
    __shared__ float vyR[VH][VW], vxR[VH][VW];
    __shared__ float mv0[VH][VW], mv1[VH][VW], mv2[VH][VW], mv3[VH][VW];
    __shared__ float ms0[IH][IW], ms1[IH][IW], ms2[IH][IW], ms3[IH][IW];
    __shared__ float buoL[VH][VW];
    __shared__ float lamL[IH][IW], lp2mL[IH][IW], muL[IH][IW];
    __shared__ float byL[VH], bxL[VW];

    const int tid = threadIdx.x;
    const int s = blockIdx.x >> 7, tile = blockIdx.x & 127;
    const int txi = tile & 7, tyi = tile >> 3;
    const int x0 = txi * TW, x1 = min(x0 + TW, NXP);
    const int y0 = tyi * TH, y1 = min(y0 + TH, NYP);
    const int w = x1 - x0, h = y1 - y0;

    // ---- zero LDS state; compute params/decay directly into LDS ----
    for (int i = tid; i < MH * MW; i += NTHR) {
        int r = i / MW, c = i - r * MW;
        syyR[r][c] = 0.0f; sxxR[r][c] = 0.0f; sxyR[r][c] = 0.0f;
    }
    for (int i = tid; i < VH * VW; i += NTHR) {
        int r = i / VW, c = i - r * VW;
        vyR[r][c] = 0.0f; vxR[r][c] = 0.0f;
        mv0[r][c] = 0.0f; mv1[r][c] = 0.0f; mv2[r][c] = 0.0f; mv3[r][c] = 0.0f;
        buoL[r][c] = 0.0f;
    }
    for (int i = tid; i < IH * IW; i += NTHR) {
        int r = i / IW, c = i - r * IW;
        ms0[r][c] = 0.0f; ms1[r][c] = 0.0f; ms2[r][c] = 0.0f; ms3[r][c] = 0.0f;
    }
    if (tid < VH) {
        int y = y0 - 2 + tid; y = min(max(y, 0), NYP - 1);
        byL[tid] = decay_at(y);
    } else if (tid >= 64 && tid < 64 + VW) {
        int i = tid - 64, x = x0 - 2 + i; x = min(max(x, 0), NXP - 1);
        bxL[i] = decay_at(x);
    }
    __syncthreads();
    {
        int ry0v = max(y0 - 2, 0), ry1v = min(y1 + 2, NYP);
        int rx0v = max(x0 - 2, 0), rx1v = min(x1 + 2, NXP);
        int rh = ry1v - ry0v, rw = rx1v - rx0v;
        for (int i = tid; i < rh * rw; i += NTHR) {
            int r = i / rw, c = i - r * rw;
            int y = ry0v + r, x = rx0v + c;
            int cy = clampi(y - PML, NYI - 1), cx = clampi(x - PML, NXI - 1);
            buoL[y - y0 + 2][x - x0 + 2] = buo[cy * NXI + cx];
        }
        for (int i = tid; i < h * w; i += NTHR) {
            int r = i / w, c = i - r * w;
            int cy = clampi(y0 + r - PML, NYI - 1), cx = clampi(x0 + c - PML, NXI - 1);
            float l = lamb[cy * NXI + cx];
            float m = mu[cy * NXI + cx];
            lamL[r][c] = l;
            lp2mL[r][c] = l + 2.0f * m;
            muL[r][c] = m;
        }
    }

    const int sy = sloc[s * 2 + 0] + PML;
    const int sx = sloc[s * 2 + 1] + PML;

    bool hasRec = false; int recOff = 0, rvi = 0, rvj = 0;
    if (tid < NSHOT * NREC) {
        int rs = tid >> 5, rr = tid & 31;
        if (rs == s) {
            int ry = rloc[(rs * NREC + rr) * 2 + 0] + PML;
            int rx = rloc[(rs * NREC + rr) * 2 + 1] + PML;
            if (ry >= y0 && ry < y1 && rx >= x0 && rx < x1) {
                hasRec = true; recOff = (rs * NREC + rr) * NT;
                rvi = ry - y0 + 2; rvj = rx - x0 + 2;
            }
        }
    }
    __syncthreads();

    // region geometry (identical to R6/R7, validated)
    const int vy0 = max(y0 - 2, 0), vy1 = min(y1 + 2, NYP);
    const int vx0 = max(x0 - 2, 0), vx1 = min(x1 + 2, NXP);
    const int cy0 = y0 + 2, cy1 = y1 - 2, cx0 = x0 + 2, cx1 = x1 - 2;
    const int cw = cx1 - cx0, ch = cy1 - cy0, nCore = cw * ch;
    const int W2 = vx1 - vx0;
    const int topH = cy0 - vy0, botH = vy1 - cy1;
    const int leftW = cx0 - vx0, rightW = vx1 - cx1;
    const int nTop = topH * W2, nBot = botH * W2;
    const int nLeft = ch * leftW, nRight = ch * rightW;
    const int nRing = nTop + nBot + nLeft + nRight;
    const int py0 = max(y0 - 4, 0), py1 = min(y1 + 4, NYP);
    const int px0 = max(x0 - 4, 0), px1 = min(x1 + 4, NXP);
    const int W4 = px1 - px0;
    const int ptH = y0 - py0, pbH = py1 - y1;
    const int plW = x0 - px0, prW = px1 - x1;
    const int nPT = ptH * W4, nPB = pbH * W4, nPL = h * plW, nPR = h * prW;
    const int nPull = nPT + nPB + nPL + nPR;

    // ---- hoisted pull-cell decode (time-invariant; nPull <= 584 < 1024) ----
    const bool hq0 = tid < nPull;
    int qg0 = 0, qo0 = 0;
    if (hq0) {
        int j = tid, y, x;
        if (j < nPT)            { y = py0 + j / W4;  x = px0 + j % W4; }
        else { j -= nPT;
        if (j < nPB)            { y = y1 + j / W4;   x = px0 + j % W4; }
        else { j -= nPB;
        if (j < nPL)            { y = y0 + j / plW;  x = px0 + j % plW; }
        else { j -= nPL;          y = y0 + j / prW;  x = x1 + j % prW; } } }
        qg0 = y * PITCH + x;
        qo0 = (y - y0 + 4) * MW + (x - x0 + 4);
    }
    float* const syyF = &syyR[0][0];
    float* const sxxF = &sxxR[0][0];
    float* const sxyF = &sxyR[0][0];

    auto doV = [&](int y, int x, float amp) {
        int hy = y - y0 + 4, hx = x - x0 + 4;
        int vi = y - y0 + 2, vj = x - x0 + 2;
        float by = byL[vi], bx = bxL[vj];
        float d1 = (C1C * (syyR[hy + 1][hx] - syyR[hy][hx]) +
                    C2C * (syyR[hy + 2][hx] - syyR[hy - 1][hx])) * RDX;   // dpy(syy)
        float m1 = by * mv0[vi][vj] + (by - 1.0f) * d1; mv0[vi][vj] = m1;
        float d2 = (C1C * (sxyR[hy][hx] - sxyR[hy][hx - 1]) +
                    C2C * (sxyR[hy][hx + 1] - sxyR[hy][hx - 2])) * RDX;   // dmx(sxy)
        float m2 = bx * mv1[vi][vj] + (bx - 1.0f) * d2; mv1[vi][vj] = m2;
        float nvy = vyR[vi][vj] + DTC * buoL[vi][vj] * (d1 + m1 + d2 + m2);
        float d3 = (C1C * (sxyR[hy][hx] - sxyR[hy - 1][hx]) +
                    C2C * (sxyR[hy + 1][hx] - sxyR[hy - 2][hx])) * RDX;   // dmy(sxy)
        float m3 = by * mv2[vi][vj] + (by - 1.0f) * d3; mv2[vi][vj] = m3;
        float d4 = (C1C * (sxxR[hy][hx + 1] - sxxR[hy][hx]) +
                    C2C * (sxxR[hy][hx + 2] - sxxR[hy][hx - 1])) * RDX;   // dpx(sxx)
        float m4 = bx * mv3[vi][vj] + (bx - 1.0f) * d4; mv3[vi][vj] = m4;
        float nvx = vxR[vi][vj] + DTC * buoL[vi][vj] * (d3 + m3 + d4 + m4);
        if (y == sy && x == sx) nvy += amp;
        vyR[vi][vj] = nvy; vxR[vi][vj] = nvx;
    };

    auto doS = [&](int ly, int lx, ull* q, unsigned tag, bool pub) {
        int vi = ly + 2, vj = lx + 2;
        float by = byL[vi], bx = bxL[vj];
        float d, m;
        d = (C1C * (vyR[vi][vj] - vyR[vi - 1][vj]) +
             C2C * (vyR[vi + 1][vj] - vyR[vi - 2][vj])) * RDX;            // dmy(vy)
        m = by * ms0[ly][lx] + (by - 1.0f) * d; ms0[ly][lx] = m;
        float dvy_dy = d + m;
        d = (C1C * (vxR[vi][vj] - vxR[vi][vj - 1]) +
             C2C * (vxR[vi][vj + 1] - vxR[vi][vj - 2])) * RDX;            // dmx(vx)
        m = bx * ms1[ly][lx] + (bx - 1.0f) * d; ms1[ly][lx] = m;
        float dvx_dx = d + m;
        float nsyy = syyR[ly + 4][lx + 4] + DTC * (lp2mL[ly][lx] * dvy_dy + lamL[ly][lx] * dvx_dx);
        float nsxx = sxxR[ly + 4][lx + 4] + DTC * (lp2mL[ly][lx] * dvx_dx + lamL[ly][lx] * dvy_dy);
        d = (C1C * (vyR[vi][vj + 1] - vyR[vi][vj]) +
             C2C * (vyR[vi][vj + 2] - vyR[vi][vj - 1])) * RDX;            // dpx(vy)
        m = bx * ms2[ly][lx] + (bx - 1.0f) * d; ms2[ly][lx] = m;
        float dvy_dx = d + m;
        d = (C1C * (vxR[vi + 1][vj] - vxR[vi][vj]) +
             C2C * (vxR[vi + 2][vj] - vxR[vi - 1][vj])) * RDX;            // dpy(vx)
        m = by * ms3[ly][lx] + (by - 1.0f) * d; ms3[ly][lx] = m;
        float dvx_dy = d + m;
        float nsxy = sxyR[ly + 4][lx + 4] + DTC * muL[ly][lx] * (dvy_dx + dvx_dy);
        syyR[ly + 4][lx + 4] = nsyy;
        sxxR[ly + 4][lx + 4] = nsxx;
        sxyR[ly + 4][lx + 4] = nsxy;
        if (pub) {
            // packed 2-word record (each 8B half self-tagged), ONE 16B store
            // at 16B stride: adjacent cells -> adjacent lanes -> coalescing.
            int gi = (y0 + ly) * PITCH + (x0 + lx);
            ull* c = q + (size_t)gi * RECU;
            unsigned syyb = __float_as_uint(nsyy);
            unsigned sxxb = __float_as_uint(nsxx);
            unsigned sxyb = __float_as_uint(nsxy);
            ull t16 = (ull)(tag & 0xffffu) << 48;
            ull w0 = t16 | ((ull)(sxxb >> 16) << 32) | (ull)syyb;
            ull w1 = t16 | ((ull)(sxxb & 0xffffu) << 32) | (ull)sxyb;
            cstore16(c, w0, w1);
        }
    };

    for (int t = 0; t < NT; ++t) {
        const float amp_t = amps[s * NT + t];

        // ---- B-issue: one 16B pull load per cell, fired up front; the
        //      latency hides under the A-phase compute ----
        const ull* bb = strips + (size_t)(((t ^ 1) & 1) * NSHOT + s) * RECU * FSTRIDE;
        const unsigned want16 = (unsigned)t & 0xffffu;
        const ull* qp0 = bb + (size_t)qg0 * RECU;
        uint4v r0;
        if (hq0) r0 = cload16_issue(qp0);

        // ---- A: velocity core (block-local; overlaps in-flight pull) ----
        for (int i = tid; i < nCore; i += NTHR) {
            int r = i / cw, c = i - r * cw;
            doV(cy0 + r, cx0 + c, amp_t);
        }

        // ---- B-resolve: wait, tag-check both self-tagged halves, spin only
        //      if the neighbor is late; reconstruct sxx bit-exactly ----
        if (hq0) {
            cload16_wait(r0);
            while (((r0.y >> 16) != want16) || ((r0.w >> 16) != want16)) {
                __builtin_amdgcn_s_sleep(1);
                r0 = cload16_sync(qp0);
            }
            syyF[qo0] = __uint_as_float(r0.x);
            sxyF[qo0] = __uint_as_float(r0.z);
            sxxF[qo0] = __uint_as_float(((r0.y & 0xffffu) << 16) | (r0.w & 0xffffu));
        }
        __syncthreads();

        // ---- C: velocity ring (+2 redundant, needs the pulled halo) ----
        for (int i = tid; i < nRing; i += NTHR) {
            int y, x, j = i;
            if (j < nTop)           { y = vy0 + j / W2;     x = vx0 + j % W2; }
            else { j -= nTop;
            if (j < nBot)           { y = cy1 + j / W2;     x = vx0 + j % W2; }
            else { j -= nBot;
            if (j < nLeft)          { y = cy0 + j / leftW;  x = vx0 + j % leftW; }
            else { j -= nLeft;        y = cy0 + j / rightW; x = cx1 + j % rightW; } } }
            doV(y, x, amp_t);
        }
        __syncthreads();

        if (hasRec) out[recOff + t] = vyR[rvi][rvj];

        // ---- D1: boundary stress (depth<4), publish immediately (tag t+1) ----
        {
            ull* pb = strips + (size_t)((t & 1) * NSHOT + s) * RECU * FSTRIDE;
            const unsigned tag = (unsigned)(t + 1);
            const int midH = h - 8;
            const int nT4 = 4 * w, nB4 = 4 * w, nL4 = midH * 4;
            const int nD1 = nT4 + nB4 + 2 * nL4;
            for (int i = tid; i < nD1; i += NTHR) {
                int ly, lx, j = i;
                if (j < nT4)      { ly = j / w;           lx = j - (j / w) * w; }
                else { j -= nT4;
                if (j < nB4)      { ly = h - 4 + j / w;   lx = j - (j / w) * w; }
                else { j -= nB4;
                if (j < nL4)      { ly = 4 + (j >> 2);    lx = j & 3; }
                else { j -= nL4;    ly = 4 + (j >> 2);    lx = w - 4 + (j & 3); } } }
                doS(ly, lx, pb, tag, true);
            }
            // ---- D2: interior stress (off the inter-block critical path) ----
            const int w8 = w - 8, nD2 = midH * w8;
            for (int i = tid; i < nD2; i += NTHR) {
                int r = i / w8, c = i - r * w8;
                doS(4 + r, 4 + c, pb, 0u, false);
            }
        }
        __syncthreads();
    }
}

// ------------------------------ fallback path (R1, proven) ------------------

__global__ __launch_bounds__(256)
void vel_kernel(float* __restrict__ ws, const float* __restrict__ params,
                const float* __restrict__ bdec, const float* __restrict__ amps,
                const int* __restrict__ sloc, int t) {
    int x = blockIdx.x * 64 + threadIdx.x;
    int y = blockIdx.y * 4 + threadIdx.y;
    int s = blockIdx.z;
    if (x >= NXP) return;
    float* F = ws + (size_t)s * 13 * FSTRIDE;
    float* vy = F; float* vx = F + FSTRIDE;
    const float* syy = F + 2 * FSTRIDE;
    const float* sxx = F + 3 * FSTRIDE;
    const float* sxy = F + 4 * FSTRIDE;
    float* msyy_y = F + 9 * FSTRIDE;  float* msxy_x = F + 10 * FSTRIDE;
    float* msxy_y = F + 11 * FSTRIDE; float* msxx_x = F + 12 * FSTRIDE;
    float by = bdec[y], bx = bdec[NYP + x];
    int idx = y * PITCH + x;
    auto ldf2 = [&](const float* f, int yy, int xx) {
        return (yy >= 0 && yy < NYP && xx >= 0 && xx < NXP) ? f[yy * PITCH + xx] : 0.0f;
    };
    float buoy = params[3 * FSTRIDE + idx];
    float d, m;
    d = (C1C * (ldf2(syy,y+1,x) - ldf2(syy,y,x)) + C2C * (ldf2(syy,y+2,x) - ldf2(syy,y-1,x))) * RDX;
    m = by * msyy_y[idx] + (by - 1.0f) * d; msyy_y[idx] = m;
    float a1 = d + m;
    d = (C1C * (ldf2(sxy,y,x) - ldf2(sxy,y,x-1)) + C2C * (ldf2(sxy,y,x+1) - ldf2(sxy,y,x-2))) * RDX;
    m = bx * msxy_x[idx] + (bx - 1.0f) * d; msxy_x[idx] = m;
    float nvy = vy[idx] + DTC * buoy * (a1 + d + m);
    d = (C1C * (ldf2(sxy,y,x) - ldf2(sxy,y-1,x)) + C2C * (ldf2(sxy,y+1,x) - ldf2(sxy,y-2,x))) * RDX;
    m = by * msxy_y[idx] + (by - 1.0f) * d; msxy_y[idx] = m;
    float a2 = d + m;
    d = (C1C * (ldf2(sxx,y,x+1) - ldf2(sxx,y,x)) + C2C * (ldf2(sxx,y,x+2) - ldf2(sxx,y,x-1))) * RDX;
    m = bx * msxx_x[idx] + (bx - 1.0f) * d; msxx_x[idx] = m;
    float nvx = vx[idx] + DTC * buoy * (a2 + d + m);
    int sy = sloc[s * 2 + 0] + PML, sx = sloc[s * 2 + 1] + PML;
    if (y == sy && x == sx) nvy += amps[s * NT + t];
    vy[idx] = nvy; vx[idx] = nvx;
}

__global__ __launch_bounds__(256)
void str_kernel(float* __restrict__ ws, const float* __restrict__ params,
                const float* __restrict__ bdec, const int* __restrict__ rloc,
                float* __restrict__ out, int t) {
    int x = blockIdx.x * 64 + threadIdx.x;
    int y = blockIdx.y * 4 + threadIdx.y;
    int s = blockIdx.z;
    float* F = ws + (size_t)s * 13 * FSTRIDE;
    const float* vy = F; const float* vx = F + FSTRIDE;
    float* syy = F + 2 * FSTRIDE; float* sxx = F + 3 * FSTRIDE; float* sxy = F + 4 * FSTRIDE;
    float* mvyy = F + 5 * FSTRIDE; float* mvyx = F + 6 * FSTRIDE;
    float* mvxy = F + 7 * FSTRIDE; float* mvxx = F + 8 * FSTRIDE;
    if (blockIdx.x == 0 && blockIdx.y == 0) {
        int tid = threadIdx.y * 64 + threadIdx.x;
        if (tid < NREC) {
            int ry = rloc[(s * NREC + tid) * 2 + 0] + PML;
            int rx = rloc[(s * NREC + tid) * 2 + 1] + PML;
            out[(s * NREC + tid) * NT + t] = vy[ry * PITCH + rx];
        }
    }
    if (x >= NXP) return;
    auto ldf2 = [&](const float* f, int yy, int xx) {
        return (yy >= 0 && yy < NYP && xx >= 0 && xx < NXP) ? f[yy * PITCH + xx] : 0.0f;
    };
    float by = bdec[y], bx = bdec[NYP + x];
    int idx = y * PITCH + x;
    float lam = params[idx], lp2m = params[FSTRIDE + idx], muv = params[2 * FSTRIDE + idx];
    float d, m;
    d = (C1C * (ldf2(vy,y,x) - ldf2(vy,y-1,x)) + C2C * (ldf2(vy,y+1,x) - ldf2(vy,y-2,x))) * RDX;
    m = by * mvyy[idx] + (by - 1.0f) * d; mvyy[idx] = m;
    float dvy_dy = d + m;
    d = (C1C * (ldf2(vx,y,x) - ldf2(vx,y,x-1)) + C2C * (ldf2(vx,y,x+1) - ldf2(vx,y,x-2))) * RDX;
    m = bx * mvxx[idx] + (bx - 1.0f) * d; mvxx[idx] = m;
    float dvx_dx = d + m;
    syy[idx] += DTC * (lp2m * dvy_dy + lam * dvx_dx);
    sxx[idx] += DTC * (lp2m * dvx_dx + lam * dvy_dy);
    d = (C1C * (ldf2(vy,y,x+1) - ldf2(vy,y,x)) + C2C * (ldf2(vy,y,x+2) - ldf2(vy,y,x-1))) * RDX;
    m = bx * mvyx[idx] + (bx - 1.0f) * d; mvyx[idx] = m;
    float dvy_dx = d + m;
    d = (C1C * (ldf2(vx,y+1,x) - ldf2(vx,y,x)) + C2C * (ldf2(vx,y+2,x) - ldf2(vx,y-1,x))) * RDX;
    m = by * mvxy[idx] + (by - 1.0f) * d; mvxy[idx] = m;
    float dvx_dy = d + m;
    sxy[idx] += DTC * muv * (dvy_dx + dvx_dy);
}

// ----------------------------------------------------------------------------

extern "C" void kernel_launch(void* const* d_in, const int* in_sizes, int n_in,
                              void* d_out, int out_size, void* d_ws, size_t ws_size,
                              hipStream_t stream) {
    const float* lamb = (const float*)d_in[0];
    const float* mu   = (const float*)d_in[1];
    const float* buo  = (const float*)d_in[2];
    const float* amps = (const float*)d_in[3];
    const int*   sloc = (const int*)d_in[4];
    const int*   rloc = (const int*)d_in[5];
    float* out = (float*)d_out;

    float* wsf = (float*)d_ws;
    // layout: [strips: 8*FSTRIDE ull (2 parities x 2 shots x 2-ull packed
    //          16B cell records)]  (persist path computes params/decay
    //          inline; region after strips unused there but kept in the
    //          `needed` check for layout parity)
    ull*   strips = (ull*)wsf;
    size_t needed = ((size_t)36 * FSTRIDE + NYP + NXP) * sizeof(float);

    if (ws_size >= needed) {
        (void)hipMemsetAsync(strips, 0, (size_t)8 * FSTRIDE * sizeof(ull), stream);
        void* args[] = {&strips, &lamb, &mu, &buo, &amps, &sloc, &rloc, &out};
        (void)hipLaunchCooperativeKernel((void*)persist6_kernel, dim3(NSHOT * TX * TY),
                                         dim3(NTHR), args, 0, stream);
    } else {
        dim3 pib(256, 1, 1), pig((NXP + 255) / 256, NYP, 1);
        float* statef = wsf + 64;
        float* paramf = wsf + 64 + (size_t)26 * FSTRIDE;
        float* bdecf  = wsf + 64 + (size_t)30 * FSTRIDE;
        (void)hipMemsetAsync(statef, 0, (size_t)26 * FSTRIDE * sizeof(float), stream);
        init_params_kernel<<<pig, pib, 0, stream>>>(lamb, mu, buo, paramf);
        init_decay_kernel<<<(NYP + NXP + 255) / 256, 256, 0, stream>>>(bdecf);
        dim3 blk(64, 4, 1), grd((NXP + 63) / 64, NYP / 4, NSHOT);
        for (int t = 0; t < NT; ++t) {
            vel_kernel<<<grd, blk, 0, stream>>>(statef, paramf, bdecf, amps, sloc, t);
            str_kernel<<<grd, blk, 0, stream>>>(statef, paramf, bdecf, rloc, out, t);
        }
    }
}